// Round 6
// baseline (289.534 us; speedup 1.0000x reference)
//
#include <hip/hip_runtime.h>
#include <math.h>

#define N_IN  128
#define N_HID 128
#define N_OUT 64

typedef _Float16 f16x8 __attribute__((ext_vector_type(8)));
typedef _Float16 f16x4 __attribute__((ext_vector_type(4)));
typedef float f32x4 __attribute__((ext_vector_type(4)));

// ---------------- CSR build ----------------
__global__ void k_hist(const int* __restrict__ dst, int E, int* __restrict__ cnt) {
  int i0 = (blockIdx.x * blockDim.x + threadIdx.x) * 4;
  int stride = gridDim.x * blockDim.x * 4;
  for (; i0 + 4 <= E; i0 += stride) {
    int4 d = *reinterpret_cast<const int4*>(&dst[i0]);
    atomicAdd(&cnt[d.x], 1);
    atomicAdd(&cnt[d.y], 1);
    atomicAdd(&cnt[d.z], 1);
    atomicAdd(&cnt[d.w], 1);
  }
  if (i0 < E)
    for (; i0 < E; ++i0) atomicAdd(&cnt[dst[i0]], 1);
}

// ---------------- W fragment pack helper ----------------
// frag elem j of lane l, k-step s, n-tile t = W[s*32 + (l>>4)*8 + j][t*16 + (l&15)]
__device__ inline void pack_one(const float* __restrict__ W, _Float16* __restrict__ Wp,
                                int N, int K, int idx) {
  int l = idx & 63;
  int ts = idx >> 6;
  int KS = K / 32;
  int t = ts / KS, s = ts - t * KS;
  int col = t * 16 + (l & 15);
  int k0 = s * 32 + (l >> 4) * 8;
  f16x8 f;
#pragma unroll
  for (int j = 0; j < 8; ++j) f[j] = (_Float16)W[(size_t)(k0 + j) * N + col];
  *reinterpret_cast<f16x8*>(&Wp[(size_t)idx * 8]) = f;
}

// ---------------- scan (block 0) + weight pack (blocks 1..5) ----------------
#define SCAN_THREADS 1024
__global__ __launch_bounds__(SCAN_THREADS) void k_scan_pack(
    const int* __restrict__ cnt, int n, int E,
    int* __restrict__ rowptr, float* __restrict__ dinv,
    const float* __restrict__ W1, const float* __restrict__ W2,
    const float* __restrict__ W3, _Float16* __restrict__ Wp1,
    _Float16* __restrict__ Wp2, _Float16* __restrict__ Wp3) {
  if (blockIdx.x > 0) {
    int idx = (int)(blockIdx.x - 1) * SCAN_THREADS + threadIdx.x;
    if (idx < 2048) pack_one(W1, Wp1, N_HID, N_IN, idx);
    else if (idx < 4096) pack_one(W2, Wp2, N_HID, N_HID, idx - 2048);
    else if (idx < 5120) pack_one(W3, Wp3, N_OUT, N_HID, idx - 4096);
    return;
  }
  __shared__ int ssum[SCAN_THREADS];
  int t = threadIdx.x;
  int C = (n + SCAN_THREADS - 1) / SCAN_THREADS;
  int base = t * C;
  int lsum = 0;
  for (int i = 0; i < C; ++i) {
    int ii = base + i;
    if (ii < n) lsum += cnt[ii];
  }
  ssum[t] = lsum;
  __syncthreads();
  for (int off = 1; off < SCAN_THREADS; off <<= 1) {
    int u = (t >= off) ? ssum[t - off] : 0;
    __syncthreads();
    ssum[t] += u;
    __syncthreads();
  }
  int pref = ssum[t] - lsum;  // exclusive
  for (int i = 0; i < C; ++i) {
    int ii = base + i;
    if (ii < n) {
      int v = cnt[ii];
      rowptr[ii] = pref;
      dinv[ii] = rsqrtf((float)v + 1.0f);  // +1 self loop
      pref += v;
    }
  }
  if (t == 0) rowptr[n] = E;
}

// fill CSR; consumes cnt via atomicSub (cnt ends at zero)
__global__ void k_fill(const int* __restrict__ src, const int* __restrict__ dst, int E,
                       const int* __restrict__ rowptr, int* __restrict__ cnt,
                       int* __restrict__ csr) {
  int i0 = (blockIdx.x * blockDim.x + threadIdx.x) * 4;
  int stride = gridDim.x * blockDim.x * 4;
  for (; i0 + 4 <= E; i0 += stride) {
    int4 d = *reinterpret_cast<const int4*>(&dst[i0]);
    int4 sr = *reinterpret_cast<const int4*>(&src[i0]);
    csr[rowptr[d.x] + atomicSub(&cnt[d.x], 1) - 1] = sr.x;
    csr[rowptr[d.y] + atomicSub(&cnt[d.y], 1) - 1] = sr.y;
    csr[rowptr[d.z] + atomicSub(&cnt[d.z], 1) - 1] = sr.z;
    csr[rowptr[d.w] + atomicSub(&cnt[d.w], 1) - 1] = sr.w;
  }
  if (i0 < E)
    for (; i0 < E; ++i0) {
      int d = dst[i0];
      csr[rowptr[d] + atomicSub(&cnt[d], 1) - 1] = src[i0];
    }
}

// ---------------- MFMA GEMM (+ dinv row scale), fp32 A, out fp16 ----------------
__global__ __launch_bounds__(256) void k_gemm1(
    const float* __restrict__ A, const _Float16* __restrict__ Wp,
    const float* __restrict__ dinv, _Float16* __restrict__ out, int M) {
  constexpr int N = N_HID, K = 128, KS = K / 32, NT = N / 16;
  int lane = threadIdx.x & 63;
  int wave = threadIdx.x >> 6;
  int rowbase = blockIdx.x * 64 + wave * 16;
  int arow = rowbase + (lane & 15);
  int arc = arow < M ? arow : M - 1;
  int k0 = (lane >> 4) * 8;

  f16x8 afrag[KS];
#pragma unroll
  for (int s = 0; s < KS; ++s) {
    float4 v0 = *reinterpret_cast<const float4*>(&A[(size_t)arc * K + s * 32 + k0]);
    float4 v1 = *reinterpret_cast<const float4*>(&A[(size_t)arc * K + s * 32 + k0 + 4]);
    f16x8 f;
    f[0] = (_Float16)v0.x; f[1] = (_Float16)v0.y;
    f[2] = (_Float16)v0.z; f[3] = (_Float16)v0.w;
    f[4] = (_Float16)v1.x; f[5] = (_Float16)v1.y;
    f[6] = (_Float16)v1.z; f[7] = (_Float16)v1.w;
    afrag[s] = f;
  }

  f32x4 acc[NT] = {};
#pragma unroll
  for (int t = 0; t < NT; ++t)
#pragma unroll
    for (int s = 0; s < KS; ++s) {
      f16x8 b = *reinterpret_cast<const f16x8*>(&Wp[((size_t)(t * KS + s) * 64 + lane) * 8]);
      acc[t] = __builtin_amdgcn_mfma_f32_16x16x32_f16(afrag[s], b, acc[t], 0, 0, 0);
    }

  int crow = (lane >> 4) * 4;
  int col = lane & 15;
#pragma unroll
  for (int r = 0; r < 4; ++r) {
    int grow = rowbase + crow + r;
    if (grow < M) {
      float dv = dinv[grow];
#pragma unroll
      for (int t = 0; t < NT; ++t)
        out[(size_t)grow * N + t * 16 + col] = (_Float16)(acc[t][r] * dv);
    }
  }
}

// ---------------- Fused aggregation + GEMM, BM=32, LDS-staged indices ----------------
// in: hs [n][128] (row-scaled); agg+bias+relu -> LDS 32x128 tile -> @ Wp -> out [n][NOUT]
#define MAXE 1536
template <int NOUT>
__global__ __launch_bounds__(256) void k_agg_gemm(
    const _Float16* __restrict__ hs, const float* __restrict__ dinv,
    const int* __restrict__ rowptr, const int* __restrict__ csr,
    const float* __restrict__ bias, const _Float16* __restrict__ Wp,
    _Float16* __restrict__ out, int n) {
  constexpr int D = 128, KS = 4, NT = NOUT / 16, TPW = NT / 4, BM = 32;
  __shared__ int sh_idx[MAXE];
  __shared__ __align__(16) _Float16 sm[BM][D + 8];
  int tid = threadIdx.x;
  int lane = tid & 63, wave = tid >> 6;
  int nodebase = blockIdx.x * BM;
  int nEnd = min(nodebase + BM, n);
  int blockBeg = rowptr[nodebase];
  int blockEnd = rowptr[nEnd];
  int total = blockEnd - blockBeg;
  int staged = min(total, MAXE);
  for (int i = tid; i < staged; i += 256) sh_idx[i] = csr[blockBeg + i];
  __syncthreads();

  int h = lane >> 5;       // half-wave
  int j = lane & 31;       // dim slot [4j, 4j+4)
  int g = wave * 2 + h;    // half-wave id 0..7, owns local rows [4g, 4g+4)

  float acc[4][4];
  int e[4], endL[4];
#pragma unroll
  for (int c = 0; c < 4; ++c) {
    int node = nodebase + g * 4 + c;
    int cn = min(node, n - 1);
    bool valid = node < n;
    e[c] = rowptr[cn] - blockBeg;
    endL[c] = valid ? rowptr[cn + 1] - blockBeg : e[c];
    f16x4 sv = *reinterpret_cast<const f16x4*>(&hs[(size_t)cn * D + 4 * j]);
#pragma unroll
    for (int k = 0; k < 4; ++k) acc[c][k] = valid ? (float)sv[k] : 0.f;
  }

  auto gather = [&](auto getidx) {
    for (;;) {
      bool active = false;
#pragma unroll
      for (int c = 0; c < 4; ++c) active |= (e[c] < endL[c]);
      if (!active) break;
      float ww[4][2];
      int id[4][2];
#pragma unroll
      for (int c = 0; c < 4; ++c)
#pragma unroll
        for (int u = 0; u < 2; ++u) {
          int p = e[c] + u;
          ww[c][u] = (p < endL[c]) ? 1.f : 0.f;
          id[c][u] = getidx(min(p, total - 1));
        }
      f16x4 vv[4][2];
#pragma unroll
      for (int c = 0; c < 4; ++c)
#pragma unroll
        for (int u = 0; u < 2; ++u)
          vv[c][u] = *reinterpret_cast<const f16x4*>(&hs[(size_t)id[c][u] * D + 4 * j]);
#pragma unroll
      for (int c = 0; c < 4; ++c) {
#pragma unroll
        for (int u = 0; u < 2; ++u)
#pragma unroll
          for (int k = 0; k < 4; ++k)
            acc[c][k] = fmaf(ww[c][u], (float)vv[c][u][k], acc[c][k]);
        e[c] += 2;
      }
    }
  };
  if (total > 0) {
    if (total <= MAXE)
      gather([&](int p) { return sh_idx[p]; });
    else
      gather([&](int p) { return csr[blockBeg + p]; });
  }

  // dinv*acc + bias, relu -> LDS tile
  {
    float4 bv = *reinterpret_cast<const float4*>(&bias[4 * j]);
    const float* bp = reinterpret_cast<const float*>(&bv);
#pragma unroll
    for (int c = 0; c < 4; ++c) {
      int node = nodebase + g * 4 + c;
      float dv = dinv[min(node, n - 1)];
      f16x4 pv;
#pragma unroll
      for (int k = 0; k < 4; ++k) pv[k] = (_Float16)fmaxf(dv * acc[c][k] + bp[k], 0.f);
      *reinterpret_cast<f16x4*>(&sm[g * 4 + c][4 * j]) = pv;
    }
  }
  __syncthreads();

  // MFMA: 2 row-tiles x TPW col-tiles per wave
  int r = lane & 15, k0 = (lane >> 4) * 8;
  f16x8 af[2][KS];
#pragma unroll
  for (int rt = 0; rt < 2; ++rt)
#pragma unroll
    for (int s = 0; s < KS; ++s)
      af[rt][s] = *reinterpret_cast<const f16x8*>(&sm[rt * 16 + r][s * 32 + k0]);

  f32x4 acc2[TPW][2] = {};
#pragma unroll
  for (int ct = 0; ct < TPW; ++ct) {
    int t = wave * TPW + ct;
#pragma unroll
    for (int s = 0; s < KS; ++s) {
      f16x8 b = *reinterpret_cast<const f16x8*>(&Wp[((size_t)(t * KS + s) * 64 + lane) * 8]);
#pragma unroll
      for (int rt = 0; rt < 2; ++rt)
        acc2[ct][rt] = __builtin_amdgcn_mfma_f32_16x16x32_f16(af[rt][s], b, acc2[ct][rt], 0, 0, 0);
    }
  }

  int crow = (lane >> 4) * 4, col = lane & 15;
#pragma unroll
  for (int rt = 0; rt < 2; ++rt)
#pragma unroll
    for (int r4 = 0; r4 < 4; ++r4) {
      int node = nodebase + rt * 16 + crow + r4;
      if (node < n) {
        float dv = dinv[node];
#pragma unroll
        for (int ct = 0; ct < TPW; ++ct)
          out[(size_t)node * NOUT + (wave * TPW + ct) * 16 + col] =
              (_Float16)(acc2[ct][rt][r4] * dv);
      }
    }
}

// ---------------- Aggregation D=64 + log_softmax, BM=32, LDS-staged indices ----------------
__global__ __launch_bounds__(256) void k_agg64_lsm(
    const _Float16* __restrict__ hs, const float* __restrict__ dinv,
    const int* __restrict__ rowptr, const int* __restrict__ csr,
    const float* __restrict__ bias, float* __restrict__ out, int n) {
  constexpr int D = 64, BM = 32;
  __shared__ int sh_idx[MAXE];
  int tid = threadIdx.x;
  int lane = tid & 63, wave = tid >> 6;
  int nodebase = blockIdx.x * BM;
  int nEnd = min(nodebase + BM, n);
  int blockBeg = rowptr[nodebase];
  int blockEnd = rowptr[nEnd];
  int total = blockEnd - blockBeg;
  int staged = min(total, MAXE);
  for (int i = tid; i < staged; i += 256) sh_idx[i] = csr[blockBeg + i];
  __syncthreads();

  int q = lane >> 4;   // quarter-wave
  int j = lane & 15;   // dim slot [4j, 4j+4)
  int g = wave * 4 + q;  // quarter id 0..15, owns local rows 2g, 2g+1

  float acc[2][4];
  int e[2], endL[2];
#pragma unroll
  for (int c = 0; c < 2; ++c) {
    int node = nodebase + g * 2 + c;
    int cn = min(node, n - 1);
    bool valid = node < n;
    e[c] = rowptr[cn] - blockBeg;
    endL[c] = valid ? rowptr[cn + 1] - blockBeg : e[c];
    f16x4 sv = *reinterpret_cast<const f16x4*>(&hs[(size_t)cn * D + 4 * j]);
#pragma unroll
    for (int k = 0; k < 4; ++k) acc[c][k] = valid ? (float)sv[k] : 0.f;
  }

  auto gather = [&](auto getidx) {
    for (;;) {
      bool active = false;
#pragma unroll
      for (int c = 0; c < 2; ++c) active |= (e[c] < endL[c]);
      if (!active) break;
      float ww[2][4];
      int id[2][4];
#pragma unroll
      for (int c = 0; c < 2; ++c)
#pragma unroll
        for (int u = 0; u < 4; ++u) {
          int p = e[c] + u;
          ww[c][u] = (p < endL[c]) ? 1.f : 0.f;
          id[c][u] = getidx(min(p, total - 1));
        }
      f16x4 vv[2][4];
#pragma unroll
      for (int c = 0; c < 2; ++c)
#pragma unroll
        for (int u = 0; u < 4; ++u)
          vv[c][u] = *reinterpret_cast<const f16x4*>(&hs[(size_t)id[c][u] * D + 4 * j]);
#pragma unroll
      for (int c = 0; c < 2; ++c) {
#pragma unroll
        for (int u = 0; u < 4; ++u)
#pragma unroll
          for (int k = 0; k < 4; ++k)
            acc[c][k] = fmaf(ww[c][u], (float)vv[c][u][k], acc[c][k]);
        e[c] += 4;
      }
    }
  };
  if (total > 0) {
    if (total <= MAXE)
      gather([&](int p) { return sh_idx[p]; });
    else
      gather([&](int p) { return csr[blockBeg + p]; });
  }

#pragma unroll
  for (int c = 0; c < 2; ++c) {
    int node = nodebase + g * 2 + c;
    int cn = min(node, n - 1);
    float dv = dinv[cn];
    float val[4];
#pragma unroll
    for (int k = 0; k < 4; ++k) val[k] = dv * acc[c][k] + bias[4 * j + k];

    float m = fmaxf(fmaxf(val[0], val[1]), fmaxf(val[2], val[3]));
#pragma unroll
    for (int o = 8; o > 0; o >>= 1) m = fmaxf(m, __shfl_xor(m, o));
    float ss = 0.f;
#pragma unroll
    for (int k = 0; k < 4; ++k) ss += expf(val[k] - m);
#pragma unroll
    for (int o = 8; o > 0; o >>= 1) ss += __shfl_xor(ss, o);
    float lse = m + logf(ss);

    if (node < n) {
      float4 o4 = make_float4(val[0] - lse, val[1] - lse, val[2] - lse, val[3] - lse);
      *reinterpret_cast<float4*>(&out[(size_t)node * D + 4 * j]) = o4;
    }
  }
}

// ---------------- launch ----------------
extern "C" void kernel_launch(void* const* d_in, const int* in_sizes, int n_in,
                              void* d_out, int out_size, void* d_ws, size_t ws_size,
                              hipStream_t stream) {
  const float* x  = (const float*)d_in[0];
  const float* W1 = (const float*)d_in[1];
  const float* b1 = (const float*)d_in[2];
  const float* W2 = (const float*)d_in[3];
  const float* b2 = (const float*)d_in[4];
  const float* W3 = (const float*)d_in[5];
  const float* b3 = (const float*)d_in[6];
  const int*   ei = (const int*)d_in[7];

  int n = in_sizes[0] / N_IN;
  int E = in_sizes[7] / 2;
  const int* src = ei;
  const int* dst = ei + E;

  char* w = (char*)d_ws;
  size_t off = 0;
  auto alloc = [&](size_t bytes) -> void* {
    void* p = w + off;
    off = (off + bytes + 255) & ~(size_t)255;
    return p;
  };
  _Float16* hs1 = (_Float16*)alloc((size_t)n * N_HID * sizeof(_Float16));
  _Float16* hs2 = (_Float16*)alloc((size_t)n * N_HID * sizeof(_Float16));
  _Float16* hs3 = (_Float16*)alloc((size_t)n * N_OUT * sizeof(_Float16));
  _Float16* Wp1 = (_Float16*)alloc((size_t)N_IN * N_HID * sizeof(_Float16));
  _Float16* Wp2 = (_Float16*)alloc((size_t)N_HID * N_HID * sizeof(_Float16));
  _Float16* Wp3 = (_Float16*)alloc((size_t)N_HID * N_OUT * sizeof(_Float16));
  float* dinv = (float*)alloc((size_t)n * sizeof(float));
  int* cnt = (int*)alloc((size_t)n * sizeof(int));
  int* rowptr = (int*)alloc((size_t)(n + 1) * sizeof(int));
  int* csr = (int*)alloc((size_t)E * sizeof(int));

  // ---- CSR by dst (+ degrees, dinv) + weight pack ----
  hipMemsetAsync(cnt, 0, (size_t)n * sizeof(int), stream);
  int blocks = min((E / 4 + 255) / 256, 1024);
  k_hist<<<blocks, 256, 0, stream>>>(dst, E, cnt);
  k_scan_pack<<<6, SCAN_THREADS, 0, stream>>>(cnt, n, E, rowptr, dinv,
                                              W1, W2, W3, Wp1, Wp2, Wp3);
  k_fill<<<blocks, 256, 0, stream>>>(src, dst, E, rowptr, cnt, csr);

  int gb = (n + 63) / 64;
  int ab = (n + 31) / 32;
  k_gemm1<<<gb, 256, 0, stream>>>(x, Wp1, dinv, hs1, n);
  k_agg_gemm<N_HID><<<ab, 256, 0, stream>>>(hs1, dinv, rowptr, csr, b1, Wp2, hs2, n);
  k_agg_gemm<N_OUT><<<ab, 256, 0, stream>>>(hs2, dinv, rowptr, csr, b2, Wp3, hs3, n);
  k_agg64_lsm<<<ab, 256, 0, stream>>>(hs3, dinv, rowptr, csr, b3, (float*)d_out, n);
}

// Round 7
// 176.147 us; speedup vs baseline: 1.6437x; 1.6437x over previous
//
#include <hip/hip_runtime.h>
#include <math.h>

#define N_IN  128
#define N_HID 128
#define N_OUT 64

typedef _Float16 f16x8 __attribute__((ext_vector_type(8)));
typedef _Float16 f16x4 __attribute__((ext_vector_type(4)));
typedef float f32x4 __attribute__((ext_vector_type(4)));

// ---------------- CSR build ----------------
__global__ void k_hist(const int* __restrict__ dst, int E, int* __restrict__ cnt) {
  int i0 = (blockIdx.x * blockDim.x + threadIdx.x) * 4;
  int stride = gridDim.x * blockDim.x * 4;
  for (; i0 + 4 <= E; i0 += stride) {
    int4 d = *reinterpret_cast<const int4*>(&dst[i0]);
    atomicAdd(&cnt[d.x], 1);
    atomicAdd(&cnt[d.y], 1);
    atomicAdd(&cnt[d.z], 1);
    atomicAdd(&cnt[d.w], 1);
  }
  if (i0 < E)
    for (; i0 < E; ++i0) atomicAdd(&cnt[dst[i0]], 1);
}

// ---- single-kernel scan: block b redundantly sums cnt[0..b*512) (L2-resident,
// coalesced), then Hillis-Steele scans its own 512-chunk. Full-grid parallel. ----
#define SCHUNK 512
__global__ __launch_bounds__(SCHUNK) void k_scan_all(
    const int* __restrict__ cnt, int n, int E,
    int* __restrict__ rowptr, float* __restrict__ dinv) {
  __shared__ int sh[SCHUNK];
  int t = threadIdx.x;
  int base = blockIdx.x * SCHUNK;
  // 1) block prefix: sum of cnt[0..base)
  int pre = 0;
  for (int i = t; i < base; i += SCHUNK) pre += cnt[i];
  sh[t] = pre;
  __syncthreads();
  for (int o = SCHUNK / 2; o > 0; o >>= 1) {
    if (t < o) sh[t] += sh[t + o];
    __syncthreads();
  }
  int blockpre = sh[0];
  __syncthreads();
  // 2) scan own chunk
  int v = (base + t < n) ? cnt[base + t] : 0;
  sh[t] = v;
  __syncthreads();
  for (int o = 1; o < SCHUNK; o <<= 1) {
    int u = (t >= o) ? sh[t - o] : 0;
    __syncthreads();
    sh[t] += u;
    __syncthreads();
  }
  int i = base + t;
  if (i < n) {
    rowptr[i] = blockpre + sh[t] - v;          // exclusive
    dinv[i] = rsqrtf((float)v + 1.0f);         // +1 self loop
    if (i == n - 1) rowptr[n] = E;
  }
}

// ---------------- W fragment pack helper ----------------
// frag elem j of lane l, k-step s, n-tile t = W[s*32 + (l>>4)*8 + j][t*16 + (l&15)]
__device__ inline void pack_one(const float* __restrict__ W, _Float16* __restrict__ Wp,
                                int N, int K, int idx) {
  int l = idx & 63;
  int ts = idx >> 6;
  int KS = K / 32;
  int t = ts / KS, s = ts - t * KS;
  int col = t * 16 + (l & 15);
  int k0 = s * 32 + (l >> 4) * 8;
  f16x8 f;
#pragma unroll
  for (int j = 0; j < 8; ++j) f[j] = (_Float16)W[(size_t)(k0 + j) * N + col];
  *reinterpret_cast<f16x8*>(&Wp[(size_t)idx * 8]) = f;
}

// ---- fill CSR (blocks < fb, consumes cnt via atomicSub) + weight pack (blocks >= fb) ----
__global__ void k_fill_pack(const int* __restrict__ src, const int* __restrict__ dst,
                            int E, const int* __restrict__ rowptr, int* __restrict__ cnt,
                            int* __restrict__ csr, int fb,
                            const float* __restrict__ W1, const float* __restrict__ W2,
                            const float* __restrict__ W3, _Float16* __restrict__ Wp1,
                            _Float16* __restrict__ Wp2, _Float16* __restrict__ Wp3) {
  if (blockIdx.x >= fb) {
    int idx = (int)(blockIdx.x - fb) * 256 + threadIdx.x;
    if (idx < 2048) pack_one(W1, Wp1, N_HID, N_IN, idx);
    else if (idx < 4096) pack_one(W2, Wp2, N_HID, N_HID, idx - 2048);
    else if (idx < 5120) pack_one(W3, Wp3, N_OUT, N_HID, idx - 4096);
    return;
  }
  int i0 = (blockIdx.x * 256 + threadIdx.x) * 4;
  int stride = fb * 256 * 4;
  for (; i0 + 4 <= E; i0 += stride) {
    int4 d = *reinterpret_cast<const int4*>(&dst[i0]);
    int4 sr = *reinterpret_cast<const int4*>(&src[i0]);
    csr[rowptr[d.x] + atomicSub(&cnt[d.x], 1) - 1] = sr.x;
    csr[rowptr[d.y] + atomicSub(&cnt[d.y], 1) - 1] = sr.y;
    csr[rowptr[d.z] + atomicSub(&cnt[d.z], 1) - 1] = sr.z;
    csr[rowptr[d.w] + atomicSub(&cnt[d.w], 1) - 1] = sr.w;
  }
  if (i0 < E && threadIdx.x == 0 && blockIdx.x == 0)
    for (int i = (E >> 2) << 2; i < E; ++i) {
      int d = dst[i];
      csr[rowptr[d] + atomicSub(&cnt[d], 1) - 1] = src[i];
    }
}

// ---------------- MFMA GEMM (+ dinv row scale), fp32 A, out fp16 ----------------
__global__ __launch_bounds__(256) void k_gemm1(
    const float* __restrict__ A, const _Float16* __restrict__ Wp,
    const float* __restrict__ dinv, _Float16* __restrict__ out, int M) {
  constexpr int N = N_HID, K = 128, KS = K / 32, NT = N / 16;
  int lane = threadIdx.x & 63;
  int wave = threadIdx.x >> 6;
  int rowbase = blockIdx.x * 64 + wave * 16;
  int arow = rowbase + (lane & 15);
  int arc = arow < M ? arow : M - 1;
  int k0 = (lane >> 4) * 8;

  f16x8 afrag[KS];
#pragma unroll
  for (int s = 0; s < KS; ++s) {
    float4 v0 = *reinterpret_cast<const float4*>(&A[(size_t)arc * K + s * 32 + k0]);
    float4 v1 = *reinterpret_cast<const float4*>(&A[(size_t)arc * K + s * 32 + k0 + 4]);
    f16x8 f;
    f[0] = (_Float16)v0.x; f[1] = (_Float16)v0.y;
    f[2] = (_Float16)v0.z; f[3] = (_Float16)v0.w;
    f[4] = (_Float16)v1.x; f[5] = (_Float16)v1.y;
    f[6] = (_Float16)v1.z; f[7] = (_Float16)v1.w;
    afrag[s] = f;
  }

  f32x4 acc[NT] = {};
#pragma unroll
  for (int t = 0; t < NT; ++t)
#pragma unroll
    for (int s = 0; s < KS; ++s) {
      f16x8 b = *reinterpret_cast<const f16x8*>(&Wp[((size_t)(t * KS + s) * 64 + lane) * 8]);
      acc[t] = __builtin_amdgcn_mfma_f32_16x16x32_f16(afrag[s], b, acc[t], 0, 0, 0);
    }

  int crow = (lane >> 4) * 4;
  int col = lane & 15;
#pragma unroll
  for (int r = 0; r < 4; ++r) {
    int grow = rowbase + crow + r;
    if (grow < M) {
      float dv = dinv[grow];
#pragma unroll
      for (int t = 0; t < NT; ++t)
        out[(size_t)grow * N + t * 16 + col] = (_Float16)(acc[t][r] * dv);
    }
  }
}

// ---------------- Fused aggregation + GEMM (+ dinv epilogue), BM=16, idx prefetch ----
// in: hs [n][128] (row-scaled); agg+bias+relu -> LDS 16x128 tile -> @ Wp -> out [n][NOUT]
template <int NOUT>
__global__ __launch_bounds__(256) void k_agg_gemm(
    const _Float16* __restrict__ hs, const float* __restrict__ dinv,
    const int* __restrict__ rowptr, const int* __restrict__ csr,
    const float* __restrict__ bias, const _Float16* __restrict__ Wp,
    _Float16* __restrict__ out, int n, int E) {
  constexpr int D = 128, KS = 4, NT = NOUT / 16, TPW = NT / 4;
  __shared__ __align__(16) _Float16 sm[16][D + 8];  // 272B row stride
  int lane = threadIdx.x & 63, wave = threadIdx.x >> 6;
  int h = lane >> 5;   // half-wave
  int j = lane & 31;   // dim slot [4j, 4j+4)
  int nodebase = blockIdx.x * 16;
  int nA = nodebase + wave * 4 + 2 * h;
  int nB = nA + 1;
  int cA = min(nA, n - 1), cB = min(nB, n - 1);
  float wsA = nA < n ? 1.f : 0.f, wsB = nB < n ? 1.f : 0.f;
  int begA = rowptr[cA], endA = nA < n ? rowptr[cA + 1] : begA;
  int begB = rowptr[cB], endB = nB < n ? rowptr[cB + 1] : begB;

  float accA[4], accB[4];
  {
    f16x4 sA = *reinterpret_cast<const f16x4*>(&hs[(size_t)cA * D + 4 * j]);
    f16x4 sB = *reinterpret_cast<const f16x4*>(&hs[(size_t)cB * D + 4 * j]);
#pragma unroll
    for (int k = 0; k < 4; ++k) {
      accA[k] = wsA * (float)sA[k];
      accB[k] = wsB * (float)sB[k];
    }
  }

  // 2 nodes per half-wave, 4-deep, with next-batch index prefetch
  int eA = begA, eB = begB;
  int ia[4], ib[4];
  float wa[4], wb[4];
  auto loadIdx = [&](int a0, int b0, int* iax, int* ibx, float* wax, float* wbx) {
#pragma unroll
    for (int u = 0; u < 4; ++u) {
      int pA = a0 + u, pB = b0 + u;
      wax[u] = pA < endA ? 1.f : 0.f;
      wbx[u] = pB < endB ? 1.f : 0.f;
      iax[u] = csr[min(pA, E - 1)];
      ibx[u] = csr[min(pB, E - 1)];
    }
  };
  bool any = (eA < endA) || (eB < endB);
  if (any) loadIdx(eA, eB, ia, ib, wa, wb);
  while (any) {
    // issue row gathers for current batch
    f16x4 va[4], vb[4];
#pragma unroll
    for (int u = 0; u < 4; ++u) {
      va[u] = *reinterpret_cast<const f16x4*>(&hs[(size_t)ia[u] * D + 4 * j]);
      vb[u] = *reinterpret_cast<const f16x4*>(&hs[(size_t)ib[u] * D + 4 * j]);
    }
    // prefetch next batch indices (independent of row loads)
    int eA2 = eA + 4, eB2 = eB + 4;
    bool any2 = (eA2 < endA) || (eB2 < endB);
    int ia2[4], ib2[4];
    float wa2[4], wb2[4];
    if (any2) loadIdx(eA2, eB2, ia2, ib2, wa2, wb2);
    // accumulate current
#pragma unroll
    for (int u = 0; u < 4; ++u)
#pragma unroll
      for (int k = 0; k < 4; ++k) {
        accA[k] = fmaf(wa[u], (float)va[u][k], accA[k]);
        accB[k] = fmaf(wb[u], (float)vb[u][k], accB[k]);
      }
    eA = eA2; eB = eB2; any = any2;
#pragma unroll
    for (int u = 0; u < 4; ++u) {
      ia[u] = ia2[u]; ib[u] = ib2[u];
      wa[u] = wa2[u]; wb[u] = wb2[u];
    }
  }

  // bias + relu -> LDS
  {
    float4 bv = *reinterpret_cast<const float4*>(&bias[4 * j]);
    const float* bp = reinterpret_cast<const float*>(&bv);
    float dvA = dinv[cA], dvB = dinv[cB];
    f16x4 pA, pB;
#pragma unroll
    for (int k = 0; k < 4; ++k) {
      pA[k] = (_Float16)fmaxf(dvA * accA[k] + bp[k], 0.f);
      pB[k] = (_Float16)fmaxf(dvB * accB[k] + bp[k], 0.f);
    }
    int lr = wave * 4 + 2 * h;
    *reinterpret_cast<f16x4*>(&sm[lr][4 * j]) = pA;
    *reinterpret_cast<f16x4*>(&sm[lr + 1][4 * j]) = pB;
  }
  __syncthreads();

  // MFMA: 16-row tile @ Wp; wave handles TPW n-tiles
  int r = lane & 15, k0 = (lane >> 4) * 8;
  f16x8 af[KS];
#pragma unroll
  for (int s = 0; s < KS; ++s)
    af[s] = *reinterpret_cast<const f16x8*>(&sm[r][s * 32 + k0]);

  f32x4 acc[TPW] = {};
#pragma unroll
  for (int tt = 0; tt < TPW; ++tt) {
    int t = wave * TPW + tt;
#pragma unroll
    for (int s = 0; s < KS; ++s) {
      f16x8 b = *reinterpret_cast<const f16x8*>(&Wp[((size_t)(t * KS + s) * 64 + lane) * 8]);
      acc[tt] = __builtin_amdgcn_mfma_f32_16x16x32_f16(af[s], b, acc[tt], 0, 0, 0);
    }
  }

  int crow = (lane >> 4) * 4, col = lane & 15;
#pragma unroll
  for (int r4 = 0; r4 < 4; ++r4) {
    int node = nodebase + crow + r4;
    if (node < n) {
      float dv = dinv[node];
#pragma unroll
      for (int tt = 0; tt < TPW; ++tt)
        out[(size_t)node * NOUT + (wave * TPW + tt) * 16 + col] =
            (_Float16)(acc[tt][r4] * dv);
    }
  }
}

// ---------------- Aggregation D=64 + log_softmax (quarter-wave per node), prefetch ----
__global__ __launch_bounds__(256) void k_agg64_lsm(
    const _Float16* __restrict__ hs, const float* __restrict__ dinv,
    const int* __restrict__ rowptr, const int* __restrict__ csr,
    const float* __restrict__ bias, float* __restrict__ out, int n, int E) {
  constexpr int D = 64;
  int lane = threadIdx.x & 63, wave = threadIdx.x >> 6;
  int q = lane >> 4, j = lane & 15;
  int node = blockIdx.x * 16 + wave * 4 + q;
  int c = min(node, n - 1);
  float ws = node < n ? 1.f : 0.f;
  int beg = rowptr[c], end = node < n ? rowptr[c + 1] : beg;

  float acc[4];
  {
    f16x4 sv = *reinterpret_cast<const f16x4*>(&hs[(size_t)c * D + 4 * j]);
#pragma unroll
    for (int k = 0; k < 4; ++k) acc[k] = ws * (float)sv[k];
  }

  int e = beg;
  int ii[4];
  float ww[4];
  auto loadIdx = [&](int e0, int* iix, float* wwx) {
#pragma unroll
    for (int u = 0; u < 4; ++u) {
      int p = e0 + u;
      wwx[u] = p < end ? 1.f : 0.f;
      iix[u] = csr[min(p, E - 1)];
    }
  };
  bool any = e < end;
  if (any) loadIdx(e, ii, ww);
  while (any) {
    f16x4 vv[4];
#pragma unroll
    for (int u = 0; u < 4; ++u)
      vv[u] = *reinterpret_cast<const f16x4*>(&hs[(size_t)ii[u] * D + 4 * j]);
    int e2 = e + 4;
    bool any2 = e2 < end;
    int ii2[4];
    float ww2[4];
    if (any2) loadIdx(e2, ii2, ww2);
#pragma unroll
    for (int u = 0; u < 4; ++u)
#pragma unroll
      for (int k = 0; k < 4; ++k) acc[k] = fmaf(ww[u], (float)vv[u][k], acc[k]);
    e = e2; any = any2;
#pragma unroll
    for (int u = 0; u < 4; ++u) { ii[u] = ii2[u]; ww[u] = ww2[u]; }
  }

  float dv = dinv[c];
  float val[4];
#pragma unroll
  for (int k = 0; k < 4; ++k) val[k] = dv * acc[k] + bias[4 * j + k];

  // log_softmax within the 16-lane quarter (xor offsets < 16 stay in-quarter)
  float m = fmaxf(fmaxf(val[0], val[1]), fmaxf(val[2], val[3]));
#pragma unroll
  for (int o = 8; o > 0; o >>= 1) m = fmaxf(m, __shfl_xor(m, o));
  float ss = 0.f;
#pragma unroll
  for (int k = 0; k < 4; ++k) ss += expf(val[k] - m);
#pragma unroll
  for (int o = 8; o > 0; o >>= 1) ss += __shfl_xor(ss, o);
  float lse = m + logf(ss);

  if (node < n) {
    float4 o4 = make_float4(val[0] - lse, val[1] - lse, val[2] - lse, val[3] - lse);
    *reinterpret_cast<float4*>(&out[(size_t)node * D + 4 * j]) = o4;
  }
}

// ---------------- launch ----------------
extern "C" void kernel_launch(void* const* d_in, const int* in_sizes, int n_in,
                              void* d_out, int out_size, void* d_ws, size_t ws_size,
                              hipStream_t stream) {
  const float* x  = (const float*)d_in[0];
  const float* W1 = (const float*)d_in[1];
  const float* b1 = (const float*)d_in[2];
  const float* W2 = (const float*)d_in[3];
  const float* b2 = (const float*)d_in[4];
  const float* W3 = (const float*)d_in[5];
  const float* b3 = (const float*)d_in[6];
  const int*   ei = (const int*)d_in[7];

  int n = in_sizes[0] / N_IN;
  int E = in_sizes[7] / 2;
  const int* src = ei;
  const int* dst = ei + E;

  char* w = (char*)d_ws;
  size_t off = 0;
  auto alloc = [&](size_t bytes) -> void* {
    void* p = w + off;
    off = (off + bytes + 255) & ~(size_t)255;
    return p;
  };
  _Float16* hs1 = (_Float16*)alloc((size_t)n * N_HID * sizeof(_Float16));
  _Float16* hs2 = (_Float16*)alloc((size_t)n * N_HID * sizeof(_Float16));
  _Float16* hs3 = (_Float16*)alloc((size_t)n * N_OUT * sizeof(_Float16));
  _Float16* Wp1 = (_Float16*)alloc((size_t)N_IN * N_HID * sizeof(_Float16));
  _Float16* Wp2 = (_Float16*)alloc((size_t)N_HID * N_HID * sizeof(_Float16));
  _Float16* Wp3 = (_Float16*)alloc((size_t)N_HID * N_OUT * sizeof(_Float16));
  float* dinv = (float*)alloc((size_t)n * sizeof(float));
  int* cnt = (int*)alloc((size_t)n * sizeof(int));
  int* rowptr = (int*)alloc((size_t)(n + 1) * sizeof(int));
  int* csr = (int*)alloc((size_t)E * sizeof(int));

  // ---- CSR by dst (+ degrees, dinv) + weight pack ----
  hipMemsetAsync(cnt, 0, (size_t)n * sizeof(int), stream);
  int fb = min((E / 4 + 255) / 256, 1024);
  k_hist<<<fb, 256, 0, stream>>>(dst, E, cnt);
  int nb = (n + SCHUNK - 1) / SCHUNK;
  k_scan_all<<<nb, SCHUNK, 0, stream>>>(cnt, n, E, rowptr, dinv);
  k_fill_pack<<<fb + 20, 256, 0, stream>>>(src, dst, E, rowptr, cnt, csr, fb,
                                           W1, W2, W3, Wp1, Wp2, Wp3);

  int gb = (n + 63) / 64;
  int ab = (n + 15) / 16;
  k_gemm1<<<gb, 256, 0, stream>>>(x, Wp1, dinv, hs1, n);
  k_agg_gemm<N_HID><<<ab, 256, 0, stream>>>(hs1, dinv, rowptr, csr, b1, Wp2, hs2, n, E);
  k_agg_gemm<N_OUT><<<ab, 256, 0, stream>>>(hs2, dinv, rowptr, csr, b2, Wp3, hs3, n, E);
  k_agg64_lsm<<<ab, 256, 0, stream>>>(hs3, dinv, rowptr, csr, b3, (float*)d_out, n, E);
}

// Round 8
// 164.372 us; speedup vs baseline: 1.7615x; 1.0716x over previous
//
#include <hip/hip_runtime.h>
#include <math.h>

#define N_IN  128
#define N_HID 128
#define N_OUT 64

typedef _Float16 f16x8 __attribute__((ext_vector_type(8)));
typedef _Float16 f16x4 __attribute__((ext_vector_type(4)));
typedef float f32x4 __attribute__((ext_vector_type(4)));

// ---------------- W fragment pack helper ----------------
// frag elem j of lane l, k-step s, n-tile t = W[s*32 + (l>>4)*8 + j][t*16 + (l&15)]
__device__ inline void pack_one(const float* __restrict__ W, _Float16* __restrict__ Wp,
                                int N, int K, int idx) {
  int l = idx & 63;
  int ts = idx >> 6;
  int KS = K / 32;
  int t = ts / KS, s = ts - t * KS;
  int col = t * 16 + (l & 15);
  int k0 = s * 32 + (l >> 4) * 8;
  f16x8 f;
#pragma unroll
  for (int j = 0; j < 8; ++j) f[j] = (_Float16)W[(size_t)(k0 + j) * N + col];
  *reinterpret_cast<f16x8*>(&Wp[(size_t)idx * 8]) = f;
}

// ---- hist (blocks < hb) + weight pack (blocks >= hb) ----
__global__ void k_hist_pack(const int* __restrict__ dst, int E, int* __restrict__ cnt,
                            int hb,
                            const float* __restrict__ W1, const float* __restrict__ W2,
                            const float* __restrict__ W3, _Float16* __restrict__ Wp1,
                            _Float16* __restrict__ Wp2, _Float16* __restrict__ Wp3) {
  if (blockIdx.x >= hb) {
    int idx = (int)(blockIdx.x - hb) * 256 + threadIdx.x;
    if (idx < 2048) pack_one(W1, Wp1, N_HID, N_IN, idx);
    else if (idx < 4096) pack_one(W2, Wp2, N_HID, N_HID, idx - 2048);
    else if (idx < 5120) pack_one(W3, Wp3, N_OUT, N_HID, idx - 4096);
    return;
  }
  int i0 = (blockIdx.x * 256 + threadIdx.x) * 4;
  int stride = hb * 256 * 4;
  for (; i0 + 4 <= E; i0 += stride) {
    int4 d = *reinterpret_cast<const int4*>(&dst[i0]);
    atomicAdd(&cnt[d.x], 1);
    atomicAdd(&cnt[d.y], 1);
    atomicAdd(&cnt[d.z], 1);
    atomicAdd(&cnt[d.w], 1);
  }
  if (blockIdx.x == 0 && threadIdx.x == 0)
    for (int i = E & ~3; i < E; ++i) atomicAdd(&cnt[dst[i]], 1);
}

// ---- single-kernel scan: block b redundantly sums cnt[0..b*512) (L2-resident,
// coalesced), then Hillis-Steele scans its own 512-chunk. Full-grid parallel. ----
#define SCHUNK 512
__global__ __launch_bounds__(SCHUNK) void k_scan_all(
    const int* __restrict__ cnt, int n, int E,
    int* __restrict__ rowptr, float* __restrict__ dinv) {
  __shared__ int sh[SCHUNK];
  int t = threadIdx.x;
  int base = blockIdx.x * SCHUNK;
  int pre = 0;
  for (int i = t; i < base; i += SCHUNK) pre += cnt[i];
  sh[t] = pre;
  __syncthreads();
  for (int o = SCHUNK / 2; o > 0; o >>= 1) {
    if (t < o) sh[t] += sh[t + o];
    __syncthreads();
  }
  int blockpre = sh[0];
  __syncthreads();
  int v = (base + t < n) ? cnt[base + t] : 0;
  sh[t] = v;
  __syncthreads();
  for (int o = 1; o < SCHUNK; o <<= 1) {
    int u = (t >= o) ? sh[t - o] : 0;
    __syncthreads();
    sh[t] += u;
    __syncthreads();
  }
  int i = base + t;
  if (i < n) {
    rowptr[i] = blockpre + sh[t] - v;          // exclusive
    dinv[i] = rsqrtf((float)v + 1.0f);         // +1 self loop
    if (i == n - 1) rowptr[n] = E;
  }
}

// ---------------- MFMA GEMM body (fp32 A, dinv scale, out fp16) ----------------
__device__ inline void gemm1_body(int bid, const float* __restrict__ A,
                                  const _Float16* __restrict__ Wp,
                                  const float* __restrict__ dinv,
                                  _Float16* __restrict__ out, int M) {
  constexpr int N = N_HID, K = 128, KS = K / 32, NT = N / 16;
  int lane = threadIdx.x & 63;
  int wave = threadIdx.x >> 6;
  int rowbase = bid * 64 + wave * 16;
  int arow = rowbase + (lane & 15);
  int arc = arow < M ? arow : M - 1;
  int k0 = (lane >> 4) * 8;

  f16x8 afrag[KS];
#pragma unroll
  for (int s = 0; s < KS; ++s) {
    float4 v0 = *reinterpret_cast<const float4*>(&A[(size_t)arc * K + s * 32 + k0]);
    float4 v1 = *reinterpret_cast<const float4*>(&A[(size_t)arc * K + s * 32 + k0 + 4]);
    f16x8 f;
    f[0] = (_Float16)v0.x; f[1] = (_Float16)v0.y;
    f[2] = (_Float16)v0.z; f[3] = (_Float16)v0.w;
    f[4] = (_Float16)v1.x; f[5] = (_Float16)v1.y;
    f[6] = (_Float16)v1.z; f[7] = (_Float16)v1.w;
    afrag[s] = f;
  }

  f32x4 acc[NT] = {};
#pragma unroll
  for (int t = 0; t < NT; ++t)
#pragma unroll
    for (int s = 0; s < KS; ++s) {
      f16x8 b = *reinterpret_cast<const f16x8*>(&Wp[((size_t)(t * KS + s) * 64 + lane) * 8]);
      acc[t] = __builtin_amdgcn_mfma_f32_16x16x32_f16(afrag[s], b, acc[t], 0, 0, 0);
    }

  int crow = (lane >> 4) * 4;
  int col = lane & 15;
#pragma unroll
  for (int r = 0; r < 4; ++r) {
    int grow = rowbase + crow + r;
    if (grow < M) {
      float dv = dinv[grow];
#pragma unroll
      for (int t = 0; t < NT; ++t)
        out[(size_t)grow * N + t * 16 + col] = (_Float16)(acc[t][r] * dv);
    }
  }
}

// ---- fill CSR (blocks < fb, consumes cnt via atomicSub) + gemm1 (blocks >= fb) ----
__global__ __launch_bounds__(256) void k_fill_gemm1(
    const int* __restrict__ src, const int* __restrict__ dst, int E,
    const int* __restrict__ rowptr, int* __restrict__ cnt, int* __restrict__ csr,
    int fb, const float* __restrict__ x, const _Float16* __restrict__ Wp1,
    const float* __restrict__ dinv, _Float16* __restrict__ hs1, int n) {
  if (blockIdx.x >= fb) {
    gemm1_body((int)blockIdx.x - fb, x, Wp1, dinv, hs1, n);
    return;
  }
  int i0 = (blockIdx.x * 256 + threadIdx.x) * 4;
  int stride = fb * 256 * 4;
  for (; i0 + 4 <= E; i0 += stride) {
    int4 d = *reinterpret_cast<const int4*>(&dst[i0]);
    int4 sr = *reinterpret_cast<const int4*>(&src[i0]);
    csr[rowptr[d.x] + atomicSub(&cnt[d.x], 1) - 1] = sr.x;
    csr[rowptr[d.y] + atomicSub(&cnt[d.y], 1) - 1] = sr.y;
    csr[rowptr[d.z] + atomicSub(&cnt[d.z], 1) - 1] = sr.z;
    csr[rowptr[d.w] + atomicSub(&cnt[d.w], 1) - 1] = sr.w;
  }
  if (blockIdx.x == 0 && threadIdx.x == 0)
    for (int i = E & ~3; i < E; ++i) {
      int d = dst[i];
      csr[rowptr[d] + atomicSub(&cnt[d], 1) - 1] = src[i];
    }
}

// ---------------- Fused aggregation + GEMM, quarter-wave f16x8 gather ----------------
// in: hs [n][128] (row-scaled); agg+bias+relu -> LDS 16x128 tile -> @ Wp -> out [n][NOUT]
// one wave VMEM inst = 4 edge-rows (64 lanes x 16B = 1KiB); 4 chains/wave.
template <int NOUT>
__global__ __launch_bounds__(256) void k_agg_gemm(
    const _Float16* __restrict__ hs, const float* __restrict__ dinv,
    const int* __restrict__ rowptr, const int* __restrict__ csr,
    const float* __restrict__ bias, const _Float16* __restrict__ Wp,
    _Float16* __restrict__ out, int n, int E) {
  constexpr int D = 128, KS = 4, NT = NOUT / 16, TPW = NT / 4;
  __shared__ __align__(16) _Float16 sm[16][D + 8];  // 272B row stride
  int lane = threadIdx.x & 63, wave = threadIdx.x >> 6;
  int q = lane >> 4;   // quarter-wave: one node per quarter
  int j = lane & 15;   // dim slot [8j, 8j+8)
  int nodebase = blockIdx.x * 16;
  int node = nodebase + wave * 4 + q;
  int cn = min(node, n - 1);
  bool valid = node < n;
  int beg = rowptr[cn], end = valid ? rowptr[cn + 1] : beg;

  float acc[8];
  {
    f16x8 sv = *reinterpret_cast<const f16x8*>(&hs[(size_t)cn * D + 8 * j]);
#pragma unroll
    for (int k = 0; k < 8; ++k) acc[k] = valid ? (float)sv[k] : 0.f;
  }

  for (int e = beg; e < end; e += 4) {
    int idx[4];
    float wt[4];
#pragma unroll
    for (int u = 0; u < 4; ++u) {
      int p = e + u;
      wt[u] = p < end ? 1.f : 0.f;
      idx[u] = csr[min(p, E - 1)];
    }
    f16x8 v[4];
#pragma unroll
    for (int u = 0; u < 4; ++u)
      v[u] = *reinterpret_cast<const f16x8*>(&hs[(size_t)idx[u] * D + 8 * j]);
#pragma unroll
    for (int u = 0; u < 4; ++u)
#pragma unroll
      for (int k = 0; k < 8; ++k)
        acc[k] = fmaf(wt[u], (float)v[u][k], acc[k]);
  }

  // dinv*acc + bias, relu -> LDS tile
  {
    float4 bv0 = *reinterpret_cast<const float4*>(&bias[8 * j]);
    float4 bv1 = *reinterpret_cast<const float4*>(&bias[8 * j + 4]);
    float bp[8] = {bv0.x, bv0.y, bv0.z, bv0.w, bv1.x, bv1.y, bv1.z, bv1.w};
    float dv = dinv[cn];
    f16x8 pv;
#pragma unroll
    for (int k = 0; k < 8; ++k) pv[k] = (_Float16)fmaxf(dv * acc[k] + bp[k], 0.f);
    *reinterpret_cast<f16x8*>(&sm[wave * 4 + q][8 * j]) = pv;
  }
  __syncthreads();

  // MFMA: 16-row tile @ Wp; wave handles TPW n-tiles
  int r = lane & 15, k0 = (lane >> 4) * 8;
  f16x8 af[KS];
#pragma unroll
  for (int s = 0; s < KS; ++s)
    af[s] = *reinterpret_cast<const f16x8*>(&sm[r][s * 32 + k0]);

  f32x4 acc2[TPW] = {};
#pragma unroll
  for (int tt = 0; tt < TPW; ++tt) {
    int t = wave * TPW + tt;
#pragma unroll
    for (int s = 0; s < KS; ++s) {
      f16x8 b = *reinterpret_cast<const f16x8*>(&Wp[((size_t)(t * KS + s) * 64 + lane) * 8]);
      acc2[tt] = __builtin_amdgcn_mfma_f32_16x16x32_f16(af[s], b, acc2[tt], 0, 0, 0);
    }
  }

  int crow = (lane >> 4) * 4, col = lane & 15;
#pragma unroll
  for (int r4 = 0; r4 < 4; ++r4) {
    int gnode = nodebase + crow + r4;
    if (gnode < n) {
      float dv = dinv[gnode];
#pragma unroll
      for (int tt = 0; tt < TPW; ++tt)
        out[(size_t)gnode * NOUT + (wave * TPW + tt) * 16 + col] =
            (_Float16)(acc2[tt][r4] * dv);
    }
  }
}

// ---------------- Aggregation D=64 + log_softmax, eighth-wave f16x8 gather ----------
// 8 lanes x 16B = one 128B row per group; 8 chains/wave; 32 nodes/block.
__global__ __launch_bounds__(256) void k_agg64_lsm(
    const _Float16* __restrict__ hs, const float* __restrict__ dinv,
    const int* __restrict__ rowptr, const int* __restrict__ csr,
    const float* __restrict__ bias, float* __restrict__ out, int n, int E) {
  constexpr int D = 64;
  int lane = threadIdx.x & 63, wave = threadIdx.x >> 6;
  int g = lane >> 3;   // eighth-wave group: one node per group
  int j = lane & 7;    // dim slot [8j, 8j+8)
  int node = blockIdx.x * 32 + wave * 8 + g;
  int cn = min(node, n - 1);
  bool valid = node < n;
  int beg = rowptr[cn], end = valid ? rowptr[cn + 1] : beg;

  float acc[8];
  {
    f16x8 sv = *reinterpret_cast<const f16x8*>(&hs[(size_t)cn * D + 8 * j]);
#pragma unroll
    for (int k = 0; k < 8; ++k) acc[k] = valid ? (float)sv[k] : 0.f;
  }

  for (int e = beg; e < end; e += 4) {
    int idx[4];
    float wt[4];
#pragma unroll
    for (int u = 0; u < 4; ++u) {
      int p = e + u;
      wt[u] = p < end ? 1.f : 0.f;
      idx[u] = csr[min(p, E - 1)];
    }
    f16x8 v[4];
#pragma unroll
    for (int u = 0; u < 4; ++u)
      v[u] = *reinterpret_cast<const f16x8*>(&hs[(size_t)idx[u] * D + 8 * j]);
#pragma unroll
    for (int u = 0; u < 4; ++u)
#pragma unroll
      for (int k = 0; k < 8; ++k)
        acc[k] = fmaf(wt[u], (float)v[u][k], acc[k]);
  }

  float dv = dinv[cn];
  float val[8];
  {
    float4 bv0 = *reinterpret_cast<const float4*>(&bias[8 * j]);
    float4 bv1 = *reinterpret_cast<const float4*>(&bias[8 * j + 4]);
    float bp[8] = {bv0.x, bv0.y, bv0.z, bv0.w, bv1.x, bv1.y, bv1.z, bv1.w};
#pragma unroll
    for (int k = 0; k < 8; ++k) val[k] = dv * acc[k] + bp[k];
  }

  // log_softmax: 8 dims/lane x 8 lanes (xor offsets < 8 stay in-group)
  float m = val[0];
#pragma unroll
  for (int k = 1; k < 8; ++k) m = fmaxf(m, val[k]);
#pragma unroll
  for (int o = 4; o > 0; o >>= 1) m = fmaxf(m, __shfl_xor(m, o));
  float ss = 0.f;
#pragma unroll
  for (int k = 0; k < 8; ++k) ss += expf(val[k] - m);
#pragma unroll
  for (int o = 4; o > 0; o >>= 1) ss += __shfl_xor(ss, o);
  float lse = m + logf(ss);

  if (valid) {
    float4 o0 = make_float4(val[0] - lse, val[1] - lse, val[2] - lse, val[3] - lse);
    float4 o1 = make_float4(val[4] - lse, val[5] - lse, val[6] - lse, val[7] - lse);
    *reinterpret_cast<float4*>(&out[(size_t)node * D + 8 * j]) = o0;
    *reinterpret_cast<float4*>(&out[(size_t)node * D + 8 * j + 4]) = o1;
  }
}

// ---------------- launch ----------------
extern "C" void kernel_launch(void* const* d_in, const int* in_sizes, int n_in,
                              void* d_out, int out_size, void* d_ws, size_t ws_size,
                              hipStream_t stream) {
  const float* x  = (const float*)d_in[0];
  const float* W1 = (const float*)d_in[1];
  const float* b1 = (const float*)d_in[2];
  const float* W2 = (const float*)d_in[3];
  const float* b2 = (const float*)d_in[4];
  const float* W3 = (const float*)d_in[5];
  const float* b3 = (const float*)d_in[6];
  const int*   ei = (const int*)d_in[7];

  int n = in_sizes[0] / N_IN;
  int E = in_sizes[7] / 2;
  const int* src = ei;
  const int* dst = ei + E;

  char* w = (char*)d_ws;
  size_t off = 0;
  auto alloc = [&](size_t bytes) -> void* {
    void* p = w + off;
    off = (off + bytes + 255) & ~(size_t)255;
    return p;
  };
  _Float16* hs1 = (_Float16*)alloc((size_t)n * N_HID * sizeof(_Float16));
  _Float16* hs2 = (_Float16*)alloc((size_t)n * N_HID * sizeof(_Float16));
  _Float16* hs3 = (_Float16*)alloc((size_t)n * N_OUT * sizeof(_Float16));
  _Float16* Wp1 = (_Float16*)alloc((size_t)N_IN * N_HID * sizeof(_Float16));
  _Float16* Wp2 = (_Float16*)alloc((size_t)N_HID * N_HID * sizeof(_Float16));
  _Float16* Wp3 = (_Float16*)alloc((size_t)N_HID * N_OUT * sizeof(_Float16));
  float* dinv = (float*)alloc((size_t)n * sizeof(float));
  int* cnt = (int*)alloc((size_t)n * sizeof(int));
  int* rowptr = (int*)alloc((size_t)(n + 1) * sizeof(int));
  int* csr = (int*)alloc((size_t)E * sizeof(int));

  // ---- CSR by dst (+ degrees, dinv) + weight pack + layer-1 GEMM ----
  hipMemsetAsync(cnt, 0, (size_t)n * sizeof(int), stream);
  int hb = min((E / 4 + 255) / 256, 1024);
  k_hist_pack<<<hb + 20, 256, 0, stream>>>(dst, E, cnt, hb, W1, W2, W3, Wp1, Wp2, Wp3);
  int nb = (n + SCHUNK - 1) / SCHUNK;
  k_scan_all<<<nb, SCHUNK, 0, stream>>>(cnt, n, E, rowptr, dinv);
  int gb = (n + 63) / 64;
  k_fill_gemm1<<<hb + gb, 256, 0, stream>>>(src, dst, E, rowptr, cnt, csr, hb,
                                            x, Wp1, dinv, hs1, n);

  int ab = (n + 15) / 16;
  int ab64 = (n + 31) / 32;
  k_agg_gemm<N_HID><<<ab, 256, 0, stream>>>(hs1, dinv, rowptr, csr, b1, Wp2, hs2, n, E);
  k_agg_gemm<N_OUT><<<ab, 256, 0, stream>>>(hs2, dinv, rowptr, csr, b2, Wp3, hs3, n, E);
  k_agg64_lsm<<<ab64, 256, 0, stream>>>(hs3, dinv, rowptr, csr, b3, (float*)d_out, n, E);
}

// Round 9
// 160.563 us; speedup vs baseline: 1.8032x; 1.0237x over previous
//
#include <hip/hip_runtime.h>
#include <math.h>

#define N_IN  128
#define N_HID 128
#define N_OUT 64

typedef _Float16 f16x8 __attribute__((ext_vector_type(8)));
typedef _Float16 f16x4 __attribute__((ext_vector_type(4)));
typedef float f32x4 __attribute__((ext_vector_type(4)));

// ---------------- W fragment pack helper ----------------
// frag elem j of lane l, k-step s, n-tile t = W[s*32 + (l>>4)*8 + j][t*16 + (l&15)]
__device__ inline void pack_one(const float* __restrict__ W, _Float16* __restrict__ Wp,
                                int N, int K, int idx) {
  int l = idx & 63;
  int ts = idx >> 6;
  int KS = K / 32;
  int t = ts / KS, s = ts - t * KS;
  int col = t * 16 + (l & 15);
  int k0 = s * 32 + (l >> 4) * 8;
  f16x8 f;
#pragma unroll
  for (int j = 0; j < 8; ++j) f[j] = (_Float16)W[(size_t)(k0 + j) * N + col];
  *reinterpret_cast<f16x8*>(&Wp[(size_t)idx * 8]) = f;
}

// ---- hist (blocks < hb, dst-partitioned passes) + weight pack (blocks >= hb) ----
#define NPASS_H 4
__global__ void k_hist_pack(const int* __restrict__ dst, int E, int n,
                            int* __restrict__ cnt, int hb,
                            const float* __restrict__ W1, const float* __restrict__ W2,
                            const float* __restrict__ W3, _Float16* __restrict__ Wp1,
                            _Float16* __restrict__ Wp2, _Float16* __restrict__ Wp3) {
  if (blockIdx.x >= hb) {
    int idx = (int)(blockIdx.x - hb) * 256 + threadIdx.x;
    if (idx < 2048) pack_one(W1, Wp1, N_HID, N_IN, idx);
    else if (idx < 4096) pack_one(W2, Wp2, N_HID, N_HID, idx - 2048);
    else if (idx < 5120) pack_one(W3, Wp3, N_OUT, N_HID, idx - 4096);
    return;
  }
  int start = (blockIdx.x * 256 + threadIdx.x) * 4;
  int stride = hb * 256 * 4;
  for (int pass = 0; pass < NPASS_H; ++pass) {
    int lo = (int)((long long)pass * n / NPASS_H);
    int hi = (int)((long long)(pass + 1) * n / NPASS_H);
    for (int i0 = start; i0 + 4 <= E; i0 += stride) {
      int4 d = *reinterpret_cast<const int4*>(&dst[i0]);
      if (d.x >= lo && d.x < hi) atomicAdd(&cnt[d.x], 1);
      if (d.y >= lo && d.y < hi) atomicAdd(&cnt[d.y], 1);
      if (d.z >= lo && d.z < hi) atomicAdd(&cnt[d.z], 1);
      if (d.w >= lo && d.w < hi) atomicAdd(&cnt[d.w], 1);
    }
  }
  if (blockIdx.x == 0 && threadIdx.x == 0)
    for (int i = E & ~3; i < E; ++i) atomicAdd(&cnt[dst[i]], 1);
}

// ---- single-kernel scan: block b redundantly sums cnt[0..b*512) (L2-resident,
// coalesced), then Hillis-Steele scans its own 512-chunk. Full-grid parallel. ----
#define SCHUNK 512
__global__ __launch_bounds__(SCHUNK) void k_scan_all(
    const int* __restrict__ cnt, int n, int E,
    int* __restrict__ rowptr, float* __restrict__ dinv) {
  __shared__ int sh[SCHUNK];
  int t = threadIdx.x;
  int base = blockIdx.x * SCHUNK;
  int pre = 0;
  for (int i = t; i < base; i += SCHUNK) pre += cnt[i];
  sh[t] = pre;
  __syncthreads();
  for (int o = SCHUNK / 2; o > 0; o >>= 1) {
    if (t < o) sh[t] += sh[t + o];
    __syncthreads();
  }
  int blockpre = sh[0];
  __syncthreads();
  int v = (base + t < n) ? cnt[base + t] : 0;
  sh[t] = v;
  __syncthreads();
  for (int o = 1; o < SCHUNK; o <<= 1) {
    int u = (t >= o) ? sh[t - o] : 0;
    __syncthreads();
    sh[t] += u;
    __syncthreads();
  }
  int i = base + t;
  if (i < n) {
    rowptr[i] = blockpre + sh[t] - v;          // exclusive
    dinv[i] = rsqrtf((float)v + 1.0f);         // +1 self loop
    if (i == n - 1) rowptr[n] = E;
  }
}

// ---------------- MFMA GEMM body (fp32 A, dinv scale, out fp16) ----------------
__device__ inline void gemm1_body(int bid, const float* __restrict__ A,
                                  const _Float16* __restrict__ Wp,
                                  const float* __restrict__ dinv,
                                  _Float16* __restrict__ out, int M) {
  constexpr int N = N_HID, K = 128, KS = K / 32, NT = N / 16;
  int lane = threadIdx.x & 63;
  int wave = threadIdx.x >> 6;
  int rowbase = bid * 64 + wave * 16;
  int arow = rowbase + (lane & 15);
  int arc = arow < M ? arow : M - 1;
  int k0 = (lane >> 4) * 8;

  f16x8 afrag[KS];
#pragma unroll
  for (int s = 0; s < KS; ++s) {
    float4 v0 = *reinterpret_cast<const float4*>(&A[(size_t)arc * K + s * 32 + k0]);
    float4 v1 = *reinterpret_cast<const float4*>(&A[(size_t)arc * K + s * 32 + k0 + 4]);
    f16x8 f;
    f[0] = (_Float16)v0.x; f[1] = (_Float16)v0.y;
    f[2] = (_Float16)v0.z; f[3] = (_Float16)v0.w;
    f[4] = (_Float16)v1.x; f[5] = (_Float16)v1.y;
    f[6] = (_Float16)v1.z; f[7] = (_Float16)v1.w;
    afrag[s] = f;
  }

  f32x4 acc[NT] = {};
#pragma unroll
  for (int t = 0; t < NT; ++t)
#pragma unroll
    for (int s = 0; s < KS; ++s) {
      f16x8 b = *reinterpret_cast<const f16x8*>(&Wp[((size_t)(t * KS + s) * 64 + lane) * 8]);
      acc[t] = __builtin_amdgcn_mfma_f32_16x16x32_f16(afrag[s], b, acc[t], 0, 0, 0);
    }

  int crow = (lane >> 4) * 4;
  int col = lane & 15;
#pragma unroll
  for (int r = 0; r < 4; ++r) {
    int grow = rowbase + crow + r;
    if (grow < M) {
      float dv = dinv[grow];
#pragma unroll
      for (int t = 0; t < NT; ++t)
        out[(size_t)grow * N + t * 16 + col] = (_Float16)(acc[t][r] * dv);
    }
  }
}

// ---- fill CSR (blocks < fb, dst-partitioned passes) + gemm1 (blocks >= fb) ----
#define NPASS_F 8
__global__ __launch_bounds__(256) void k_fill_gemm1(
    const int* __restrict__ src, const int* __restrict__ dst, int E, int n,
    const int* __restrict__ rowptr, int* __restrict__ cnt, int* __restrict__ csr,
    int fb, const float* __restrict__ x, const _Float16* __restrict__ Wp1,
    const float* __restrict__ dinv, _Float16* __restrict__ hs1) {
  if (blockIdx.x >= fb) {
    gemm1_body((int)blockIdx.x - fb, x, Wp1, dinv, hs1, n);
    return;
  }
  int start = (blockIdx.x * 256 + threadIdx.x) * 4;
  int stride = fb * 256 * 4;
  for (int pass = 0; pass < NPASS_F; ++pass) {
    int lo = (int)((long long)pass * n / NPASS_F);
    int hi = (int)((long long)(pass + 1) * n / NPASS_F);
    for (int i0 = start; i0 + 4 <= E; i0 += stride) {
      int4 d = *reinterpret_cast<const int4*>(&dst[i0]);
      int4 sr = *reinterpret_cast<const int4*>(&src[i0]);
      if (d.x >= lo && d.x < hi) csr[rowptr[d.x] + atomicSub(&cnt[d.x], 1) - 1] = sr.x;
      if (d.y >= lo && d.y < hi) csr[rowptr[d.y] + atomicSub(&cnt[d.y], 1) - 1] = sr.y;
      if (d.z >= lo && d.z < hi) csr[rowptr[d.z] + atomicSub(&cnt[d.z], 1) - 1] = sr.z;
      if (d.w >= lo && d.w < hi) csr[rowptr[d.w] + atomicSub(&cnt[d.w], 1) - 1] = sr.w;
    }
  }
  if (blockIdx.x == 0 && threadIdx.x == 0)
    for (int i = E & ~3; i < E; ++i) {
      int d = dst[i];
      csr[rowptr[d] + atomicSub(&cnt[d], 1) - 1] = src[i];
    }
}

// ---------------- Fused aggregation + GEMM, quarter-wave f16x8 gather ----------------
// in: hs [n][128] (row-scaled); agg+bias+relu -> LDS 16x128 tile -> @ Wp -> out [n][NOUT]
template <int NOUT>
__global__ __launch_bounds__(256) void k_agg_gemm(
    const _Float16* __restrict__ hs, const float* __restrict__ dinv,
    const int* __restrict__ rowptr, const int* __restrict__ csr,
    const float* __restrict__ bias, const _Float16* __restrict__ Wp,
    _Float16* __restrict__ out, int n, int E) {
  constexpr int D = 128, KS = 4, NT = NOUT / 16, TPW = NT / 4;
  __shared__ __align__(16) _Float16 sm[16][D + 8];  // 272B row stride
  int lane = threadIdx.x & 63, wave = threadIdx.x >> 6;
  int q = lane >> 4;   // quarter-wave: one node per quarter
  int j = lane & 15;   // dim slot [8j, 8j+8)
  int nodebase = blockIdx.x * 16;
  int node = nodebase + wave * 4 + q;
  int cn = min(node, n - 1);
  bool valid = node < n;
  int beg = rowptr[cn], end = valid ? rowptr[cn + 1] : beg;

  float acc[8];
  {
    f16x8 sv = *reinterpret_cast<const f16x8*>(&hs[(size_t)cn * D + 8 * j]);
#pragma unroll
    for (int k = 0; k < 8; ++k) acc[k] = valid ? (float)sv[k] : 0.f;
  }

  for (int e = beg; e < end; e += 4) {
    int idx[4];
    float wt[4];
#pragma unroll
    for (int u = 0; u < 4; ++u) {
      int p = e + u;
      wt[u] = p < end ? 1.f : 0.f;
      idx[u] = csr[min(p, E - 1)];
    }
    f16x8 v[4];
#pragma unroll
    for (int u = 0; u < 4; ++u)
      v[u] = *reinterpret_cast<const f16x8*>(&hs[(size_t)idx[u] * D + 8 * j]);
#pragma unroll
    for (int u = 0; u < 4; ++u)
#pragma unroll
      for (int k = 0; k < 8; ++k)
        acc[k] = fmaf(wt[u], (float)v[u][k], acc[k]);
  }

  // dinv*acc + bias, relu -> LDS tile
  {
    float4 bv0 = *reinterpret_cast<const float4*>(&bias[8 * j]);
    float4 bv1 = *reinterpret_cast<const float4*>(&bias[8 * j + 4]);
    float bp[8] = {bv0.x, bv0.y, bv0.z, bv0.w, bv1.x, bv1.y, bv1.z, bv1.w};
    float dv = dinv[cn];
    f16x8 pv;
#pragma unroll
    for (int k = 0; k < 8; ++k) pv[k] = (_Float16)fmaxf(dv * acc[k] + bp[k], 0.f);
    *reinterpret_cast<f16x8*>(&sm[wave * 4 + q][8 * j]) = pv;
  }
  __syncthreads();

  // MFMA: 16-row tile @ Wp; wave handles TPW n-tiles
  int r = lane & 15, k0 = (lane >> 4) * 8;
  f16x8 af[KS];
#pragma unroll
  for (int s = 0; s < KS; ++s)
    af[s] = *reinterpret_cast<const f16x8*>(&sm[r][s * 32 + k0]);

  f32x4 acc2[TPW] = {};
#pragma unroll
  for (int tt = 0; tt < TPW; ++tt) {
    int t = wave * TPW + tt;
#pragma unroll
    for (int s = 0; s < KS; ++s) {
      f16x8 b = *reinterpret_cast<const f16x8*>(&Wp[((size_t)(t * KS + s) * 64 + lane) * 8]);
      acc2[tt] = __builtin_amdgcn_mfma_f32_16x16x32_f16(af[s], b, acc2[tt], 0, 0, 0);
    }
  }

  int crow = (lane >> 4) * 4, col = lane & 15;
#pragma unroll
  for (int r4 = 0; r4 < 4; ++r4) {
    int gnode = nodebase + crow + r4;
    if (gnode < n) {
      float dv = dinv[gnode];
#pragma unroll
      for (int tt = 0; tt < TPW; ++tt)
        out[(size_t)gnode * NOUT + (wave * TPW + tt) * 16 + col] =
            (_Float16)(acc2[tt][r4] * dv);
    }
  }
}

// ---------------- Aggregation D=64 + log_softmax, eighth-wave f16x8 gather ----------
__global__ __launch_bounds__(256) void k_agg64_lsm(
    const _Float16* __restrict__ hs, const float* __restrict__ dinv,
    const int* __restrict__ rowptr, const int* __restrict__ csr,
    const float* __restrict__ bias, float* __restrict__ out, int n, int E) {
  constexpr int D = 64;
  int lane = threadIdx.x & 63, wave = threadIdx.x >> 6;
  int g = lane >> 3;   // eighth-wave group: one node per group
  int j = lane & 7;    // dim slot [8j, 8j+8)
  int node = blockIdx.x * 32 + wave * 8 + g;
  int cn = min(node, n - 1);
  bool valid = node < n;
  int beg = rowptr[cn], end = valid ? rowptr[cn + 1] : beg;

  float acc[8];
  {
    f16x8 sv = *reinterpret_cast<const f16x8*>(&hs[(size_t)cn * D + 8 * j]);
#pragma unroll
    for (int k = 0; k < 8; ++k) acc[k] = valid ? (float)sv[k] : 0.f;
  }

  for (int e = beg; e < end; e += 4) {
    int idx[4];
    float wt[4];
#pragma unroll
    for (int u = 0; u < 4; ++u) {
      int p = e + u;
      wt[u] = p < end ? 1.f : 0.f;
      idx[u] = csr[min(p, E - 1)];
    }
    f16x8 v[4];
#pragma unroll
    for (int u = 0; u < 4; ++u)
      v[u] = *reinterpret_cast<const f16x8*>(&hs[(size_t)idx[u] * D + 8 * j]);
#pragma unroll
    for (int u = 0; u < 4; ++u)
#pragma unroll
      for (int k = 0; k < 8; ++k)
        acc[k] = fmaf(wt[u], (float)v[u][k], acc[k]);
  }

  float dv = dinv[cn];
  float val[8];
  {
    float4 bv0 = *reinterpret_cast<const float4*>(&bias[8 * j]);
    float4 bv1 = *reinterpret_cast<const float4*>(&bias[8 * j + 4]);
    float bp[8] = {bv0.x, bv0.y, bv0.z, bv0.w, bv1.x, bv1.y, bv1.z, bv1.w};
#pragma unroll
    for (int k = 0; k < 8; ++k) val[k] = dv * acc[k] + bp[k];
  }

  // log_softmax: 8 dims/lane x 8 lanes (xor offsets < 8 stay in-group)
  float m = val[0];
#pragma unroll
  for (int k = 1; k < 8; ++k) m = fmaxf(m, val[k]);
#pragma unroll
  for (int o = 4; o > 0; o >>= 1) m = fmaxf(m, __shfl_xor(m, o));
  float ss = 0.f;
#pragma unroll
  for (int k = 0; k < 8; ++k) ss += expf(val[k] - m);
#pragma unroll
  for (int o = 4; o > 0; o >>= 1) ss += __shfl_xor(ss, o);
  float lse = m + logf(ss);

  if (valid) {
    float4 o0 = make_float4(val[0] - lse, val[1] - lse, val[2] - lse, val[3] - lse);
    float4 o1 = make_float4(val[4] - lse, val[5] - lse, val[6] - lse, val[7] - lse);
    *reinterpret_cast<float4*>(&out[(size_t)node * D + 8 * j]) = o0;
    *reinterpret_cast<float4*>(&out[(size_t)node * D + 8 * j + 4]) = o1;
  }
}

// ---------------- launch ----------------
extern "C" void kernel_launch(void* const* d_in, const int* in_sizes, int n_in,
                              void* d_out, int out_size, void* d_ws, size_t ws_size,
                              hipStream_t stream) {
  const float* x  = (const float*)d_in[0];
  const float* W1 = (const float*)d_in[1];
  const float* b1 = (const float*)d_in[2];
  const float* W2 = (const float*)d_in[3];
  const float* b2 = (const float*)d_in[4];
  const float* W3 = (const float*)d_in[5];
  const float* b3 = (const float*)d_in[6];
  const int*   ei = (const int*)d_in[7];

  int n = in_sizes[0] / N_IN;
  int E = in_sizes[7] / 2;
  const int* src = ei;
  const int* dst = ei + E;

  char* w = (char*)d_ws;
  size_t off = 0;
  auto alloc = [&](size_t bytes) -> void* {
    void* p = w + off;
    off = (off + bytes + 255) & ~(size_t)255;
    return p;
  };
  _Float16* hs1 = (_Float16*)alloc((size_t)n * N_HID * sizeof(_Float16));
  _Float16* hs2 = (_Float16*)alloc((size_t)n * N_HID * sizeof(_Float16));
  _Float16* hs3 = (_Float16*)alloc((size_t)n * N_OUT * sizeof(_Float16));
  _Float16* Wp1 = (_Float16*)alloc((size_t)N_IN * N_HID * sizeof(_Float16));
  _Float16* Wp2 = (_Float16*)alloc((size_t)N_HID * N_HID * sizeof(_Float16));
  _Float16* Wp3 = (_Float16*)alloc((size_t)N_HID * N_OUT * sizeof(_Float16));
  float* dinv = (float*)alloc((size_t)n * sizeof(float));
  int* cnt = (int*)alloc((size_t)n * sizeof(int));
  int* rowptr = (int*)alloc((size_t)(n + 1) * sizeof(int));
  int* csr = (int*)alloc((size_t)E * sizeof(int));

  // ---- CSR by dst (+ degrees, dinv) + weight pack + layer-1 GEMM ----
  hipMemsetAsync(cnt, 0, (size_t)n * sizeof(int), stream);
  int hb = min((E / 4 + 255) / 256, 1024);
  k_hist_pack<<<hb + 20, 256, 0, stream>>>(dst, E, n, cnt, hb,
                                           W1, W2, W3, Wp1, Wp2, Wp3);
  int nb = (n + SCHUNK - 1) / SCHUNK;
  k_scan_all<<<nb, SCHUNK, 0, stream>>>(cnt, n, E, rowptr, dinv);
  int gb = (n + 63) / 64;
  k_fill_gemm1<<<hb + gb, 256, 0, stream>>>(src, dst, E, n, rowptr, cnt, csr, hb,
                                            x, Wp1, dinv, hs1);

  int ab = (n + 15) / 16;
  int ab64 = (n + 31) / 32;
  k_agg_gemm<N_HID><<<ab, 256, 0, stream>>>(hs1, dinv, rowptr, csr, b1, Wp2, hs2, n, E);
  k_agg_gemm<N_OUT><<<ab, 256, 0, stream>>>(hs2, dinv, rowptr, csr, b2, Wp3, hs3, n, E);
  k_agg64_lsm<<<ab64, 256, 0, stream>>>(hs3, dinv, rowptr, csr, b3, (float*)d_out, n, E);
}